// Round 1
// baseline (2957.922 us; speedup 1.0000x reference)
//
#include <hip/hip_runtime.h>
#include <math.h>

#define DEVFN __device__ __forceinline__

static constexpr int PIXN = 36864;   // 192*192
static constexpr int NTOK = 2304;    // 48*48

// ---------------- helpers ----------------
DEVFN void ins5(float* a, float v) {
  if (v <= a[4]) return;
  a[4] = v;
#pragma unroll
  for (int k = 4; k > 0; --k) {
    if (a[k] > a[k-1]) { float tmp = a[k]; a[k] = a[k-1]; a[k-1] = tmp; }
  }
}

DEVFN void merge5(float* a, const float* o) {
  float r[5]; int i = 0, j = 0;
#pragma unroll
  for (int k = 0; k < 5; ++k) {
    bool ta = (j >= 5) || (i < 5 && a[i] >= o[j]);
    r[k] = ta ? a[i] : o[j];
    if (ta) ++i; else ++j;
  }
#pragma unroll
  for (int k = 0; k < 5; ++k) a[k] = r[k];
}

// ---------------- K1: 1x1 conv  x(128) -> qk(256) + v0(128), channel-major out
__global__ __launch_bounds__(256) void k1_conv1x1(
    const float* __restrict__ x,
    const float* __restrict__ qk_w, const float* __restrict__ qk_b,
    const float* __restrict__ v_w, const float* __restrict__ v_b,
    float* __restrict__ qk_buf, float* __restrict__ v0_buf) {
  __shared__ __align__(16) float xs[128][132];
  const int b = blockIdx.y;
  const int pix0 = blockIdx.x * 128;
  const int t = threadIdx.x;
  {
    const int p4 = (t & 31) * 4;
    const int cbase = t >> 5;
    for (int cb = 0; cb < 128; cb += 8) {
      const int ci = cb + cbase;
      const float4 v = *reinterpret_cast<const float4*>(
          &x[((size_t)b * 128 + ci) * PIXN + pix0 + p4]);
      xs[p4 + 0][ci] = v.x; xs[p4 + 1][ci] = v.y;
      xs[p4 + 2][ci] = v.z; xs[p4 + 3][ci] = v.w;
    }
  }
  __syncthreads();
  const int p = t & 127;
  const int coh = t >> 7;
  for (int chunk = 0; chunk < 24; ++chunk) {
    const int co0 = chunk * 16 + coh * 8;
    const bool is_qk = (co0 < 256);
    const float* wb = is_qk ? (qk_w + (size_t)co0 * 128) : (v_w + (size_t)(co0 - 256) * 128);
    const float* bb = is_qk ? (qk_b + co0) : (v_b + (co0 - 256));
    float acc[8];
#pragma unroll
    for (int e = 0; e < 8; ++e) acc[e] = bb[e];
    for (int ci = 0; ci < 128; ci += 4) {
      const float4 xv = *reinterpret_cast<const float4*>(&xs[p][ci]);
#pragma unroll
      for (int e = 0; e < 8; ++e) {
        const float4 wv = *reinterpret_cast<const float4*>(&wb[(size_t)e * 128 + ci]);
        acc[e] += xv.x * wv.x + xv.y * wv.y + xv.z * wv.z + xv.w * wv.w;
      }
    }
    float* dst = is_qk ? &qk_buf[((size_t)b * 256 + co0) * PIXN + pix0 + p]
                       : &v0_buf[((size_t)b * 128 + (co0 - 256)) * PIXN + pix0 + p];
#pragma unroll
    for (int e = 0; e < 8; ++e) dst[(size_t)e * PIXN] = acc[e];
  }
}

// ---------------- K2: 3x3 depthwise on 384 channels (qk 256 -> qkd, v 128 -> vd)
__global__ __launch_bounds__(256) void k2_dw3x3(
    const float* __restrict__ qk_buf, const float* __restrict__ v0_buf,
    const float* __restrict__ qk_dw_w, const float* __restrict__ qk_dw_b,
    const float* __restrict__ v_dw_w, const float* __restrict__ v_dw_b,
    float* __restrict__ qkd, float* __restrict__ vd) {
  const long gid = (long)blockIdx.x * 256 + threadIdx.x;  // < 2*384*PIXN
  const int pix = (int)(gid % PIXN);
  const long rr = gid / PIXN;
  const int ch = (int)(rr % 384);
  const int b = (int)(rr / 384);
  const int py = pix / 192, px = pix % 192;
  const float* src; const float* wv; float bias; float* dst;
  if (ch < 256) {
    src = qk_buf + ((size_t)b * 256 + ch) * PIXN;
    wv = qk_dw_w + ch * 9; bias = qk_dw_b[ch];
    dst = qkd + ((size_t)b * 256 + ch) * PIXN + pix;
  } else {
    const int c = ch - 256;
    src = v0_buf + ((size_t)b * 128 + c) * PIXN;
    wv = v_dw_w + c * 9; bias = v_dw_b[c];
    dst = vd + ((size_t)b * 128 + c) * PIXN + pix;
  }
  float acc = bias;
#pragma unroll
  for (int dy = -1; dy <= 1; ++dy) {
    const int yy = py + dy;
    if ((unsigned)yy >= 192u) continue;
#pragma unroll
    for (int dx = -1; dx <= 1; ++dx) {
      const int xx = px + dx;
      if ((unsigned)xx >= 192u) continue;
      acc += wv[(dy + 1) * 3 + (dx + 1)] * src[yy * 192 + xx];
    }
  }
  *dst = acc;
}

// ---------------- K2T: vd [b][c][pix] -> v_new tokens in d_out (v slot f=1)
__global__ __launch_bounds__(256) void k2t_transpose(
    const float* __restrict__ vd, float* __restrict__ vout) {
  __shared__ float ts[64][197];
  const int chalf = blockIdx.x;
  const int py = blockIdx.y;
  const int b = blockIdx.z;
  const int t = threadIdx.x;
  for (int i = t; i < 64 * 48; i += 256) {
    const int c = i / 48;
    const int x4 = (i % 48) * 4;
    const float4 v = *reinterpret_cast<const float4*>(
        &vd[((size_t)b * 128 + chalf * 64 + c) * PIXN + py * 192 + x4]);
    ts[c][x4 + 0] = v.x; ts[c][x4 + 1] = v.y; ts[c][x4 + 2] = v.z; ts[c][x4 + 3] = v.w;
  }
  __syncthreads();
  const int c = t & 63;
  const int grp = t >> 6;
  const int hi = py % 48, p1 = py / 48;
  for (int p2 = 0; p2 < 4; ++p2) {
    for (int wi = grp; wi < 48; wi += 4) {
      const int tok = hi * 48 + wi;
      vout[(((size_t)b * 2 + 1) * NTOK + tok) * 2048 + (p1 * 4 + p2) * 128 + chalf * 64 + c]
          = ts[c][p2 * 48 + wi];
    }
  }
}

// ---------------- K34A: 1x1 conv on qkd halves -> q2full / k2full (pixel-major out)
__global__ __launch_bounds__(256) void k34a_conv1x1(
    const float* __restrict__ qkd,
    const float* __restrict__ q2_w, const float* __restrict__ q2_b,
    const float* __restrict__ k2_w, const float* __restrict__ k2_b,
    float* __restrict__ q2full, float* __restrict__ k2full) {
  __shared__ __align__(16) float xs[128][132];
  const int b = blockIdx.y;
  const int half = blockIdx.z;
  const int pix0 = blockIdx.x * 128;
  const int t = threadIdx.x;
  const float* w = half ? k2_w : q2_w;
  const float* bias = half ? k2_b : q2_b;
  float* dstb = half ? k2full : q2full;
  {
    const int p4 = (t & 31) * 4;
    const int cbase = t >> 5;
    for (int cb = 0; cb < 128; cb += 8) {
      const int ci = cb + cbase;
      const float4 v = *reinterpret_cast<const float4*>(
          &qkd[((size_t)b * 256 + half * 128 + ci) * PIXN + pix0 + p4]);
      xs[p4 + 0][ci] = v.x; xs[p4 + 1][ci] = v.y;
      xs[p4 + 2][ci] = v.z; xs[p4 + 3][ci] = v.w;
    }
  }
  __syncthreads();
  const int p = t & 127;
  const int coh = t >> 7;
  for (int chunk = 0; chunk < 16; ++chunk) {
    const int co0 = chunk * 16 + coh * 8;
    float acc[8];
#pragma unroll
    for (int e = 0; e < 8; ++e) acc[e] = bias[co0 + e];
    for (int ci = 0; ci < 128; ci += 4) {
      const float4 xv = *reinterpret_cast<const float4*>(&xs[p][ci]);
#pragma unroll
      for (int e = 0; e < 8; ++e) {
        const float4 wv = *reinterpret_cast<const float4*>(&w[(size_t)(co0 + e) * 128 + ci]);
        acc[e] += xv.x * wv.x + xv.y * wv.y + xv.z * wv.z + xv.w * wv.w;
      }
    }
    float* dst = &dstb[((size_t)b * PIXN + pix0 + p) * 256 + co0];
    float4 o0, o1;
    o0.x = acc[0]; o0.y = acc[1]; o0.z = acc[2]; o0.w = acc[3];
    o1.x = acc[4]; o1.y = acc[5]; o1.z = acc[6]; o1.w = acc[7];
    *reinterpret_cast<float4*>(dst) = o0;
    *reinterpret_cast<float4*>(dst + 4) = o1;
  }
}

// ---------------- K34B: 4x4 stride-4 pad-1 depthwise + l2norm -> q_n (ws) / k_new (d_out)
__global__ __launch_bounds__(256) void k34b_down(
    const float* __restrict__ q2full, const float* __restrict__ k2full,
    const float* __restrict__ q2_dw_w, const float* __restrict__ q2_dw_b,
    const float* __restrict__ k2_dw_w, const float* __restrict__ k2_dw_b,
    float* __restrict__ q_n, float* __restrict__ kout) {
  const int tok = blockIdx.x;
  const int half = blockIdx.y;
  const int b = blockIdx.z;
  const int hi = tok / 48, wi = tok % 48;
  const int co = threadIdx.x;
  const float* src = half ? k2full : q2full;
  const float* dww = half ? k2_dw_w : q2_dw_w;
  float acc = half ? k2_dw_b[co] : q2_dw_b[co];
#pragma unroll
  for (int kh = 0; kh < 4; ++kh) {
    const int py = hi * 4 - 1 + kh;
    if ((unsigned)py >= 192u) continue;
#pragma unroll
    for (int kw = 0; kw < 4; ++kw) {
      const int px = wi * 4 - 1 + kw;
      if ((unsigned)px >= 192u) continue;
      acc += dww[co * 16 + kh * 4 + kw] * src[((size_t)b * PIXN + py * 192 + px) * 256 + co];
    }
  }
  float ss = acc * acc;
#pragma unroll
  for (int o = 32; o; o >>= 1) ss += __shfl_xor(ss, o);
  __shared__ float wsum[4];
  const int lane = threadIdx.x & 63, wv = threadIdx.x >> 6;
  if (lane == 0) wsum[wv] = ss;
  __syncthreads();
  const float tot = wsum[0] + wsum[1] + wsum[2] + wsum[3];
  const float denom = fmaxf(sqrtf(tot), 1e-12f);
  const float o = acc / denom;
  if (half == 0) q_n[((size_t)b * NTOK + tok) * 256 + co] = o;
  else kout[(((size_t)b * 2 + 1) * NTOK + tok) * 256 + co] = o;
}

// ---------------- K5: attn = temp * q_n @ k_f^T   (per b,f)  64x64 f32 tile GEMM
__global__ __launch_bounds__(256) void k5_qk(
    const float* __restrict__ q_n, const float* __restrict__ k_cached,
    const float* __restrict__ kout, const float* __restrict__ temp_p,
    float* __restrict__ attn) {
  __shared__ __align__(16) float As[64][68];
  __shared__ __align__(16) float Bs[64][68];
  const int i0 = blockIdx.x * 64, j0 = blockIdx.y * 64;
  const int bf = blockIdx.z;
  const int b = bf / 3, f = bf % 3;
  const float* A = q_n + (size_t)b * NTOK * 256;
  const float* Bm = (f < 2) ? (k_cached + ((size_t)b * 2 + f) * NTOK * 256)
                            : (kout + ((size_t)b * 2 + 1) * NTOK * 256);
  const int t = threadIdx.x;
  float acc[4][4] = {};
  for (int kb = 0; kb < 256; kb += 64) {
#pragma unroll
    for (int pass = 0; pass < 4; ++pass) {
      const int idx = t + pass * 256;
      const int row = idx >> 4, k4 = (idx & 15) * 4;
      *reinterpret_cast<float4*>(&As[row][k4]) =
          *reinterpret_cast<const float4*>(&A[(size_t)(i0 + row) * 256 + kb + k4]);
      *reinterpret_cast<float4*>(&Bs[row][k4]) =
          *reinterpret_cast<const float4*>(&Bm[(size_t)(j0 + row) * 256 + kb + k4]);
    }
    __syncthreads();
    const int ti = t & 15, tj = t >> 4;
    for (int kk = 0; kk < 64; kk += 4) {
      float4 av[4], bv[4];
#pragma unroll
      for (int r = 0; r < 4; ++r) av[r] = *reinterpret_cast<const float4*>(&As[ti * 4 + r][kk]);
#pragma unroll
      for (int s = 0; s < 4; ++s) bv[s] = *reinterpret_cast<const float4*>(&Bs[tj * 4 + s][kk]);
#pragma unroll
      for (int r = 0; r < 4; ++r)
#pragma unroll
        for (int s = 0; s < 4; ++s)
          acc[r][s] += av[r].x * bv[s].x + av[r].y * bv[s].y +
                       av[r].z * bv[s].z + av[r].w * bv[s].w;
    }
    __syncthreads();
  }
  const float temp = temp_p[0];
  const int ti = t & 15, tj = t >> 4;
#pragma unroll
  for (int r = 0; r < 4; ++r) {
    float4 o;
    o.x = acc[r][0] * temp; o.y = acc[r][1] * temp;
    o.z = acc[r][2] * temp; o.w = acc[r][3] * temp;
    *reinterpret_cast<float4*>(
        &attn[((size_t)bf * NTOK + i0 + ti * 4 + r) * NTOK + j0 + tj * 4]) = o;
  }
}

// ---------------- K6: per-row top-5 threshold + local mask + clipped softmax -> compact
__global__ __launch_bounds__(256) void k6_softmax(
    const float* __restrict__ attn, int* __restrict__ cntb,
    int* __restrict__ idxb, float* __restrict__ valb) {
  const int row = blockIdx.x;           // bf*NTOK + i
  const int i = row % NTOK;
  const float* a = attn + (size_t)row * NTOK;
  const int t = threadIdx.x;
  float v[9];
#pragma unroll
  for (int s = 0; s < 9; ++s) v[s] = a[s * 256 + t];
  const float NINF = -__builtin_inff();
  float t5[5] = {NINF, NINF, NINF, NINF, NINF};
#pragma unroll
  for (int s = 0; s < 9; ++s) ins5(t5, v[s]);
#pragma unroll
  for (int off = 1; off < 64; off <<= 1) {
    float o5[5];
#pragma unroll
    for (int r = 0; r < 5; ++r) o5[r] = __shfl_xor(t5[r], off);
    merge5(t5, o5);
  }
  __shared__ float wl[4][5];
  __shared__ float wred[4];
  __shared__ float s_kth, s_max, s_sum;
  __shared__ int s_cnt;
  const int lane = t & 63, wv = t >> 6;
  if (lane == 0) {
#pragma unroll
    for (int r = 0; r < 5; ++r) wl[wv][r] = t5[r];
  }
  if (t == 0) s_cnt = 0;
  __syncthreads();
  if (t == 0) {
    float m5[5] = {NINF, NINF, NINF, NINF, NINF};
    for (int w = 0; w < 4; ++w)
      for (int r = 0; r < 5; ++r) ins5(m5, wl[w][r]);
    s_kth = m5[4];
  }
  __syncthreads();
  const float kth = s_kth;
  const int yi = i / 48, xi = i % 48;
  float val[9]; bool keep[9];
  float mx = NINF;
#pragma unroll
  for (int s = 0; s < 9; ++s) {
    const int j = s * 256 + t;
    const int yj = j / 48, xj = j % 48;
    const int dy = yi > yj ? yi - yj : yj - yi;
    const int dx = xi > xj ? xi - xj : xj - xi;
    const int m = (v[s] >= kth ? 1 : 0) + ((dy + dx) <= 4 ? 1 : 0);
    const float w = v[s] * (float)m;
    keep[s] = (m > 0) && (w != 0.0f);
    val[s] = w;
    if (keep[s]) mx = fmaxf(mx, w);
  }
#pragma unroll
  for (int o = 32; o; o >>= 1) mx = fmaxf(mx, __shfl_xor(mx, o));
  if (lane == 0) wred[wv] = mx;
  __syncthreads();
  if (t == 0) s_max = fmaxf(fmaxf(wred[0], wred[1]), fmaxf(wred[2], wred[3]));
  __syncthreads();
  const float rmax = s_max;
  float ex[9];
  float sum = 0.f;
#pragma unroll
  for (int s = 0; s < 9; ++s) {
    ex[s] = keep[s] ? expf(val[s] - rmax) : 0.f;
    sum += ex[s];
  }
#pragma unroll
  for (int o = 32; o; o >>= 1) sum += __shfl_xor(sum, o);
  __syncthreads();
  if (lane == 0) wred[wv] = sum;
  __syncthreads();
  if (t == 0) s_sum = wred[0] + wred[1] + wred[2] + wred[3];
  __syncthreads();
  const float inv = 1.0f / s_sum;
#pragma unroll
  for (int s = 0; s < 9; ++s) {
    if (keep[s]) {
      const int slot = atomicAdd(&s_cnt, 1);
      if (slot < 64) {
        idxb[(size_t)row * 64 + slot] = s * 256 + t;
        valb[(size_t)row * 64 + slot] = ex[s] * inv;
      }
    }
  }
  __syncthreads();
  if (t == 0) cntb[row] = s_cnt < 64 ? s_cnt : 64;
}

// ---------------- K7: sparse PV  pv[row] = sum_e a_e * v[j_e]
__global__ __launch_bounds__(256) void k7_pv(
    const int* __restrict__ cntb, const int* __restrict__ idxb, const float* __restrict__ valb,
    const float* __restrict__ v_cached, const float* __restrict__ vout,
    float* __restrict__ pv) {
  const int row = blockIdx.x;
  const int b = row / (3 * NTOK);
  const int f = (row / NTOK) % 3;
  const float* vsrc = (f < 2) ? (v_cached + ((size_t)b * 2 + f) * NTOK * 2048)
                              : (vout + ((size_t)b * 2 + 1) * NTOK * 2048);
  const int n = cntb[row];
  const int d0 = threadIdx.x * 8;
  float4 a0 = {0, 0, 0, 0}, a1 = {0, 0, 0, 0};
  for (int e = 0; e < n; ++e) {
    const int jj = idxb[(size_t)row * 64 + e];
    const float w = valb[(size_t)row * 64 + e];
    const float* vr = vsrc + (size_t)jj * 2048 + d0;
    const float4 x0 = *reinterpret_cast<const float4*>(vr);
    const float4 x1 = *reinterpret_cast<const float4*>(vr + 4);
    a0.x += w * x0.x; a0.y += w * x0.y; a0.z += w * x0.z; a0.w += w * x0.w;
    a1.x += w * x1.x; a1.y += w * x1.y; a1.z += w * x1.z; a1.w += w * x1.w;
  }
  float* dst = pv + (size_t)row * 2048 + d0;
  *reinterpret_cast<float4*>(dst) = a0;
  *reinterpret_cast<float4*>(dst + 4) = a1;
}

// ---------------- K8: proj (1x1, 128->128) + scatter tokens -> NCHW out images
__global__ __launch_bounds__(384) void k8_proj(
    const float* __restrict__ pv, const float* __restrict__ proj_w,
    const float* __restrict__ proj_b, float* __restrict__ outb) {
  __shared__ __align__(16) float ps[96][132];
  const int half = blockIdx.x;
  const int h = blockIdx.y;
  const int bf = blockIdx.z;
  const int hi = h % 48, p1 = h / 48;
  const int t = threadIdx.x;
#pragma unroll
  for (int r = 0; r < 8; ++r) {
    const int fidx = t + r * 384;          // 0..3071
    const int pix = fidx >> 5, ci4 = (fidx & 31) * 4;
    const int w = half * 96 + pix;
    const int p2 = w / 48, wi = w % 48;
    const float* src = pv + ((size_t)bf * NTOK + hi * 48 + wi) * 2048 + (p1 * 4 + p2) * 128 + ci4;
    *reinterpret_cast<float4*>(&ps[pix][ci4]) = *reinterpret_cast<const float4*>(src);
  }
  __syncthreads();
  const int pix = t % 96, cg = t / 96;     // cg in 0..3
  const int w = half * 96 + pix;
  float acc[32];
#pragma unroll
  for (int cc = 0; cc < 32; ++cc) acc[cc] = proj_b[cg * 32 + cc];
  for (int ci4 = 0; ci4 < 128; ci4 += 4) {
    const float4 p4 = *reinterpret_cast<const float4*>(&ps[pix][ci4]);
#pragma unroll
    for (int cc = 0; cc < 32; ++cc) {
      const float4 w4 = *reinterpret_cast<const float4*>(&proj_w[(size_t)(cg * 32 + cc) * 128 + ci4]);
      acc[cc] += p4.x * w4.x + p4.y * w4.y + p4.z * w4.z + p4.w * w4.w;
    }
  }
#pragma unroll
  for (int cc = 0; cc < 32; ++cc) {
    outb[((size_t)bf * 128 + cg * 32 + cc) * PIXN + h * 192 + w] = acc[cc];
  }
}

// ---------------- launch ----------------
extern "C" void kernel_launch(void* const* d_in, const int* in_sizes, int n_in,
                              void* d_out, int out_size, void* d_ws, size_t ws_size,
                              hipStream_t stream) {
  const float* x = (const float*)d_in[0];
  const float* k_cached = (const float*)d_in[1];
  const float* v_cached = (const float*)d_in[2];
  const float* temperature = (const float*)d_in[3];
  const float* qk_w = (const float*)d_in[4];
  const float* qk_b = (const float*)d_in[5];
  const float* qk_dw_w = (const float*)d_in[6];
  const float* qk_dw_b = (const float*)d_in[7];
  const float* v_w = (const float*)d_in[8];
  const float* v_b = (const float*)d_in[9];
  const float* v_dw_w = (const float*)d_in[10];
  const float* v_dw_b = (const float*)d_in[11];
  const float* k2_w = (const float*)d_in[12];
  const float* k2_b = (const float*)d_in[13];
  const float* k2_dw_w = (const float*)d_in[14];
  const float* k2_dw_b = (const float*)d_in[15];
  const float* q2_w = (const float*)d_in[16];
  const float* q2_b = (const float*)d_in[17];
  const float* q2_dw_w = (const float*)d_in[18];
  const float* q2_dw_b = (const float*)d_in[19];
  const float* proj_w = (const float*)d_in[20];
  const float* proj_b = (const float*)d_in[21];

  float* out = (float*)d_out;
  float* ws = (float*)d_ws;

  // workspace layout (float offsets); phase-aliased
  const size_t QK_OFF = 0;                 // 18,874,368  (K1 out, dead after K2)
  const size_t V0_OFF = 18874368;          //  9,437,184  (K1 out, dead after K2)
  const size_t QKD_OFF = 28311552;         // 18,874,368  (K2 out, dead after K34A)
  // aliases: k2full @0 (K34A out, dead after K34B); attn @0 (31,850,496, K5..K6);
  //          pv @0 (28,311,552, K7..K8)
  const size_t QN_OFF = 31850496;          //  1,179,648
  const size_t CNT_OFF = 33030144;         //     13,824 ints
  const size_t IDX_OFF = 33043968;         //    884,736 ints
  const size_t VAL_OFF = 33928704;         //    884,736 floats  (end 34,813,440 < 47,185,920)

  // d_out layout (float offsets)
  const size_t KOUT_OFF = 28311552;
  const size_t VOUT_OFF = 30670848;
  // out-image region [0..28,311,552) used as scratch before K8:
  const size_t VD_OFF = 0;                 // vd: 9,437,184
  const size_t Q2F_OFF = 9437184;          // q2full: 18,874,368

  // passthrough copies: k_out[:,0]=k_cached[:,1], v_out[:,0]=v_cached[:,1]
  for (int b = 0; b < 2; ++b) {
    hipMemcpyAsync(out + KOUT_OFF + ((size_t)b * 2) * NTOK * 256,
                   k_cached + ((size_t)b * 2 + 1) * NTOK * 256,
                   (size_t)NTOK * 256 * sizeof(float), hipMemcpyDeviceToDevice, stream);
    hipMemcpyAsync(out + VOUT_OFF + ((size_t)b * 2) * NTOK * 2048,
                   v_cached + ((size_t)b * 2 + 1) * NTOK * 2048,
                   (size_t)NTOK * 2048 * sizeof(float), hipMemcpyDeviceToDevice, stream);
  }

  k1_conv1x1<<<dim3(288, 2), 256, 0, stream>>>(x, qk_w, qk_b, v_w, v_b,
                                               ws + QK_OFF, ws + V0_OFF);
  k2_dw3x3<<<110592, 256, 0, stream>>>(ws + QK_OFF, ws + V0_OFF,
                                       qk_dw_w, qk_dw_b, v_dw_w, v_dw_b,
                                       ws + QKD_OFF, out + VD_OFF);
  k2t_transpose<<<dim3(2, 192, 2), 256, 0, stream>>>(out + VD_OFF, out + VOUT_OFF);
  k34a_conv1x1<<<dim3(288, 2, 2), 256, 0, stream>>>(ws + QKD_OFF, q2_w, q2_b, k2_w, k2_b,
                                                    out + Q2F_OFF, ws + 0);
  k34b_down<<<dim3(2304, 2, 2), 256, 0, stream>>>(out + Q2F_OFF, ws + 0,
                                                  q2_dw_w, q2_dw_b, k2_dw_w, k2_dw_b,
                                                  ws + QN_OFF, out + KOUT_OFF);
  k5_qk<<<dim3(36, 36, 6), 256, 0, stream>>>(ws + QN_OFF, k_cached, out + KOUT_OFF,
                                             temperature, ws + 0);
  k6_softmax<<<13824, 256, 0, stream>>>(ws + 0, (int*)(ws + CNT_OFF),
                                        (int*)(ws + IDX_OFF), ws + VAL_OFF);
  k7_pv<<<13824, 256, 0, stream>>>((const int*)(ws + CNT_OFF), (const int*)(ws + IDX_OFF),
                                   ws + VAL_OFF, v_cached, out + VOUT_OFF, ws + 0);
  k8_proj<<<dim3(2, 192, 6), 384, 0, stream>>>(ws + 0, proj_w, proj_b, out + 0);
}